// Round 3
// baseline (459.481 us; speedup 1.0000x reference)
//
#include <hip/hip_runtime.h>
#include <hip/hip_bf16.h>

#define N_ROWS 8192
#define D_DIM  256

// loss_i = log(sum_{j != i} exp(<x_i,y_j>/T)) - <x_i,y_i>/T ; out = mean_i loss_i
static constexpr float kScaleLog2 = 20.609929155556627f;  // (1/0.07) * log2(e)
static constexpr float kInvT      = 14.285714285714286f;  // 1/0.07

typedef __bf16 bf16x8 __attribute__((ext_vector_type(8)));
typedef float  f32x4  __attribute__((ext_vector_type(4)));

// ---------------- fp32 -> bf16 pre-convert + ws init ---------------------------
__global__ __launch_bounds__(256)
void cvt_bf16_kernel(const float* __restrict__ x, const float* __restrict__ y,
                     __bf16* __restrict__ xb, __bf16* __restrict__ yb,
                     float* __restrict__ rowsum, unsigned int* __restrict__ done) {
  if (blockIdx.x == 0) {
    for (int i = threadIdx.x; i < N_ROWS; i += 256) rowsum[i] = 0.f;
    if (threadIdx.x == 0) *done = 0u;
  }
  const int per_mat = N_ROWS * D_DIM / 8;  // 8 elements per thread
  int idx = blockIdx.x * blockDim.x + threadIdx.x;
  const float* src = x;
  __bf16* dst = xb;
  int i = idx;
  if (idx >= per_mat) { src = y; dst = yb; i = idx - per_mat; }
  float4 a = ((const float4*)src)[2 * (size_t)i];
  float4 b = ((const float4*)src)[2 * (size_t)i + 1];
  bf16x8 v;
  v[0] = (__bf16)a.x; v[1] = (__bf16)a.y; v[2] = (__bf16)a.z; v[3] = (__bf16)a.w;
  v[4] = (__bf16)b.x; v[5] = (__bf16)b.y; v[6] = (__bf16)b.z; v[7] = (__bf16)b.w;
  *(bf16x8*)(dst + (size_t)i * 8) = v;
}

// ---------------- barrier-free GEMM: fragments direct from global (L1/L2-hot) --
// Block tile 128x128, 256 threads = 4 waves (2x2), wave tile 64x64 via 4x4
// MFMA 16x16x32 bf16. No LDS in the main loop; register double-buffered
// prefetch of the next K-step's fragments. 8x8 supertile swizzle for L2.
__global__ __launch_bounds__(256, 2)
void infonce_gemm(const __bf16* __restrict__ X, const __bf16* __restrict__ Y,
                  float* __restrict__ rowsum, float* __restrict__ diag,
                  unsigned int* __restrict__ done, float* __restrict__ out) {
  __shared__ float red[256];
  __shared__ unsigned int ticket;

  // 8x8 supertiles of 8x8 blocks over a 64x64 block grid
  const int idx    = blockIdx.x;
  const int sb     = idx >> 6;
  const int within = idx & 63;
  const int bi = ((sb >> 3) << 3) + (within >> 3);
  const int bj = ((sb & 7) << 3) + (within & 7);

  const int t    = threadIdx.x;
  const int lane = t & 63;
  const int wave = t >> 6;        // 0..3
  const int wm   = wave >> 1;     // 0..1
  const int wn   = wave & 1;      // 0..1
  const int quad = lane >> 4;     // 0..3
  const int l15  = lane & 15;

  // A frag (mt, ks): X[(bi*128 + wm*64 + mt*16 + l15) * 256 + ks*32 + quad*8]
  const __bf16* Abase = X + (size_t)(bi * 128 + wm * 64 + l15) * D_DIM + quad * 8;
  const __bf16* Bbase = Y + (size_t)(bj * 128 + wn * 64 + l15) * D_DIM + quad * 8;

  f32x4 acc[4][4];
#pragma unroll
  for (int a = 0; a < 4; ++a)
#pragma unroll
    for (int b = 0; b < 4; ++b) acc[a][b] = (f32x4){0.f, 0.f, 0.f, 0.f};

  bf16x8 af[4], bfr[4];
#pragma unroll
  for (int mt = 0; mt < 4; ++mt)
    af[mt] = *(const bf16x8*)(Abase + mt * 16 * D_DIM);
#pragma unroll
  for (int nt = 0; nt < 4; ++nt)
    bfr[nt] = *(const bf16x8*)(Bbase + nt * 16 * D_DIM);

#pragma unroll
  for (int ks = 0; ks < D_DIM / 32; ++ks) {   // 8 K-steps
    bf16x8 an[4], bn[4];
    if (ks < D_DIM / 32 - 1) {
      const int ko = (ks + 1) * 32;
#pragma unroll
      for (int mt = 0; mt < 4; ++mt)
        an[mt] = *(const bf16x8*)(Abase + mt * 16 * D_DIM + ko);
#pragma unroll
      for (int nt = 0; nt < 4; ++nt)
        bn[nt] = *(const bf16x8*)(Bbase + nt * 16 * D_DIM + ko);
    }
#pragma unroll
    for (int mt = 0; mt < 4; ++mt)
#pragma unroll
      for (int nt = 0; nt < 4; ++nt)
        acc[mt][nt] = __builtin_amdgcn_mfma_f32_16x16x32_bf16(
            af[mt], bfr[nt], acc[mt][nt], 0, 0, 0);
    if (ks < D_DIM / 32 - 1) {
#pragma unroll
      for (int mt = 0; mt < 4; ++mt) af[mt] = an[mt];
#pragma unroll
      for (int nt = 0; nt < 4; ++nt) bfr[nt] = bn[nt];
    }
  }

  // epilogue: exp + row-sum (excluding diagonal), diag capture
  const int gi_base = bi * 128 + wm * 64;
  const int gj_base = bj * 128 + wn * 64;
#pragma unroll
  for (int mt = 0; mt < 4; ++mt) {
#pragma unroll
    for (int r = 0; r < 4; ++r) {
      const int gi = gi_base + mt * 16 + quad * 4 + r;
      float part = 0.f;
#pragma unroll
      for (int nt = 0; nt < 4; ++nt) {
        const int gj = gj_base + nt * 16 + l15;
        float s = acc[mt][nt][r];
        if (gi == gj) {
          diag[gi] = s;           // unique writer
        } else {
          part += exp2f(s * kScaleLog2);
        }
      }
      part += __shfl_xor(part, 1);
      part += __shfl_xor(part, 2);
      part += __shfl_xor(part, 4);
      part += __shfl_xor(part, 8);
      if (l15 == 0) atomicAdd(&rowsum[gi], part);
    }
  }

  // ---- last-block finalize (ticket pattern, device-scope) ----
  __threadfence();                       // release rowsum atomics + diag stores
  if (t == 0) ticket = atomicAdd(done, 1u);
  __syncthreads();
  if (ticket == (unsigned int)(gridDim.x - 1)) {
    __threadfence();                     // acquire
    float local = 0.f;
    for (int i = t; i < N_ROWS; i += 256)
      local += __logf(rowsum[i]) - diag[i] * kInvT;
    red[t] = local;
    __syncthreads();
    for (int s = 128; s > 0; s >>= 1) {
      if (t < s) red[t] += red[t + s];
      __syncthreads();
    }
    if (t == 0) out[0] = red[0] / (float)N_ROWS;
  }
}

extern "C" void kernel_launch(void* const* d_in, const int* in_sizes, int n_in,
                              void* d_out, int out_size, void* d_ws, size_t ws_size,
                              hipStream_t stream) {
  const float* x = (const float*)d_in[0];
  const float* y = (const float*)d_in[1];
  float* out = (float*)d_out;

  // ws layout: rowsum[N] f32 | diag[N] f32 | done u32 (padded to 16B) | xb | yb
  float* rowsum = (float*)d_ws;
  float* diag   = rowsum + N_ROWS;
  unsigned int* done = (unsigned int*)(diag + N_ROWS);
  __bf16* xb = (__bf16*)((char*)d_ws + 2 * N_ROWS * sizeof(float) + 16);
  __bf16* yb = xb + (size_t)N_ROWS * D_DIM;

  int cvt_blocks = 2 * N_ROWS * D_DIM / 8 / 256;  // 2048
  cvt_bf16_kernel<<<cvt_blocks, 256, 0, stream>>>(x, y, xb, yb, rowsum, done);

  infonce_gemm<<<4096, 256, 0, stream>>>(xb, yb, rowsum, diag, done, out);
}

// Round 4
// 421.346 us; speedup vs baseline: 1.0905x; 1.0905x over previous
//
#include <hip/hip_runtime.h>
#include <hip/hip_bf16.h>

#define N_ROWS 8192
#define D_DIM  256

// loss_i = log(sum_{j != i} exp(<x_i,y_j>/T)) - <x_i,y_i>/T ; out = mean_i loss_i
static constexpr float kScaleLog2 = 20.609929155556627f;  // (1/0.07) * log2(e)
static constexpr float kInvT      = 14.285714285714286f;  // 1/0.07

typedef __bf16 bf16x8 __attribute__((ext_vector_type(8)));
typedef float  f32x4  __attribute__((ext_vector_type(4)));

// async 16B global->LDS: LDS dest = wave-uniform base + lane*16
__device__ __forceinline__ void gl_lds16(const void* g, void* l) {
  __builtin_amdgcn_global_load_lds(
      (const __attribute__((address_space(1))) void*)g,
      (__attribute__((address_space(3))) void*)l, 16, 0, 0);
}

// ---------------- fp32 -> bf16 pre-convert + ws init ---------------------------
__global__ __launch_bounds__(256)
void cvt_bf16_kernel(const float* __restrict__ x, const float* __restrict__ y,
                     __bf16* __restrict__ xb, __bf16* __restrict__ yb,
                     float* __restrict__ rowsum, unsigned int* __restrict__ done) {
  if (blockIdx.x == 0) {
    for (int i = threadIdx.x; i < N_ROWS; i += 256) rowsum[i] = 0.f;
    if (threadIdx.x == 0) *done = 0u;
  }
  const int per_mat = N_ROWS * D_DIM / 8;  // 8 elements per thread
  int idx = blockIdx.x * blockDim.x + threadIdx.x;
  const float* src = x;
  __bf16* dst = xb;
  int i = idx;
  if (idx >= per_mat) { src = y; dst = yb; i = idx - per_mat; }
  float4 a = ((const float4*)src)[2 * (size_t)i];
  float4 b = ((const float4*)src)[2 * (size_t)i + 1];
  bf16x8 v;
  v[0] = (__bf16)a.x; v[1] = (__bf16)a.y; v[2] = (__bf16)a.z; v[3] = (__bf16)a.w;
  v[4] = (__bf16)b.x; v[5] = (__bf16)b.y; v[6] = (__bf16)b.z; v[7] = (__bf16)b.w;
  *(bf16x8*)(dst + (size_t)i * 8) = v;
}

// ---------------- fused GEMM + exp + row-sum + last-block finalize -------------
// Block tile 128x128, BK=64, 256 threads = 4 waves (2x2), wave tile 64x64 via
// 4x4 MFMA 16x16x32 bf16. Staging via global_load_lds(16B); the XOR swizzle is
// applied on the GLOBAL source side so the LDS image equals R1's verified
// layout (slot s holds chunk (s&7)^(row&7) of row s>>3) and fragment
// ds_read_b128s stay conflict-free.
__global__ __launch_bounds__(256, 3)
void infonce_gemm(const __bf16* __restrict__ X, const __bf16* __restrict__ Y,
                  float* __restrict__ rowsum, float* __restrict__ diag,
                  unsigned int* __restrict__ done, float* __restrict__ out) {
  constexpr int BM = 128, BK = 64;
  __shared__ __bf16 Xs[BM * BK];   // 16 KB
  __shared__ __bf16 Ys[BM * BK];   // 16 KB
  __shared__ unsigned int ticket;

  // 8x8 supertiles over the 64x64 block grid (L2 locality)
  const int idx    = blockIdx.x;
  const int sb     = idx >> 6;
  const int within = idx & 63;
  const int bi = ((sb >> 3) << 3) + (within >> 3);
  const int bj = ((sb & 7) << 3) + (within & 7);

  const int t    = threadIdx.x;
  const int lane = t & 63;
  const int wave = t >> 6;        // 0..3
  const int wm   = wave >> 1;     // 0..1
  const int wn   = wave & 1;      // 0..1
  const int quad = lane >> 4;     // 0..3
  const int l15  = lane & 15;

  const __bf16* Xblk = X + (size_t)(bi * BM) * D_DIM;
  const __bf16* Yblk = Y + (size_t)(bj * BM) * D_DIM;

  f32x4 acc[4][4];
#pragma unroll
  for (int a = 0; a < 4; ++a)
#pragma unroll
    for (int b = 0; b < 4; ++b) acc[a][b] = (f32x4){0.f, 0.f, 0.f, 0.f};

  // per-thread staging geometry (slot = LDS 16B-chunk index, wave-contiguous)
  for (int kt = 0; kt < D_DIM / BK; ++kt) {
    if (kt) __syncthreads();
    const int k0 = kt * BK;
#pragma unroll
    for (int it = 0; it < 4; ++it) {
      const int c0  = (it * 4 + wave) * 64;  // wave-uniform slot base
      const int s   = c0 + lane;
      const int row = s >> 3;
      const int ch  = (s & 7) ^ (row & 7);   // inverse swizzle on global side
      const size_t goff = (size_t)row * D_DIM + k0 + ch * 8;
      gl_lds16(Xblk + goff, &Xs[c0 * 8]);
      gl_lds16(Yblk + goff, &Ys[c0 * 8]);
    }
    __syncthreads();

#pragma unroll
    for (int ks = 0; ks < 2; ++ks) {  // two k=32 steps per BK
      bf16x8 af[4], bfr[4];
#pragma unroll
      for (int mt = 0; mt < 4; ++mt) {
        int row = wm * 64 + mt * 16 + l15;
        int ch  = ks * 4 + quad;
        int chs = ch ^ (row & 7);
        af[mt] = *(const bf16x8*)(&Xs[row * BK + chs * 8]);
      }
#pragma unroll
      for (int nt = 0; nt < 4; ++nt) {
        int row = wn * 64 + nt * 16 + l15;
        int ch  = ks * 4 + quad;
        int chs = ch ^ (row & 7);
        bfr[nt] = *(const bf16x8*)(&Ys[row * BK + chs * 8]);
      }
#pragma unroll
      for (int mt = 0; mt < 4; ++mt)
#pragma unroll
        for (int nt = 0; nt < 4; ++nt)
          acc[mt][nt] = __builtin_amdgcn_mfma_f32_16x16x32_bf16(
              af[mt], bfr[nt], acc[mt][nt], 0, 0, 0);
    }
  }

  // epilogue: exp + row-sum (excluding diagonal), diag capture
  const int gi_base = bi * BM + wm * 64;
  const int gj_base = bj * BM + wn * 64;
#pragma unroll
  for (int mt = 0; mt < 4; ++mt) {
#pragma unroll
    for (int r = 0; r < 4; ++r) {
      const int gi = gi_base + mt * 16 + quad * 4 + r;
      float part = 0.f;
#pragma unroll
      for (int nt = 0; nt < 4; ++nt) {
        const int gj = gj_base + nt * 16 + l15;
        float s = acc[mt][nt][r];
        if (gi == gj) {
          diag[gi] = s;           // unique writer
        } else {
          part += exp2f(s * kScaleLog2);
        }
      }
      part += __shfl_xor(part, 1);
      part += __shfl_xor(part, 2);
      part += __shfl_xor(part, 4);
      part += __shfl_xor(part, 8);
      if (l15 == 0) atomicAdd(&rowsum[gi], part);
    }
  }

  // ---- last-block finalize (ticket pattern, device-scope) ----
  __threadfence();                       // release rowsum atomics + diag stores
  if (t == 0) ticket = atomicAdd(done, 1u);
  __syncthreads();
  if (ticket == (unsigned int)(gridDim.x - 1)) {
    __threadfence();                     // acquire
    float local = 0.f;
    for (int i = t; i < N_ROWS; i += 256)
      local += __logf(rowsum[i]) - diag[i] * kInvT;
    float* red = (float*)Xs;
    red[t] = local;
    __syncthreads();
    for (int s = 128; s > 0; s >>= 1) {
      if (t < s) red[t] += red[t + s];
      __syncthreads();
    }
    if (t == 0) out[0] = red[0] / (float)N_ROWS;
  }
}

extern "C" void kernel_launch(void* const* d_in, const int* in_sizes, int n_in,
                              void* d_out, int out_size, void* d_ws, size_t ws_size,
                              hipStream_t stream) {
  const float* x = (const float*)d_in[0];
  const float* y = (const float*)d_in[1];
  float* out = (float*)d_out;

  // ws layout: rowsum[N] f32 | diag[N] f32 | done u32 (padded to 16B) | xb | yb
  float* rowsum = (float*)d_ws;
  float* diag   = rowsum + N_ROWS;
  unsigned int* done = (unsigned int*)(diag + N_ROWS);
  __bf16* xb = (__bf16*)((char*)d_ws + 2 * N_ROWS * sizeof(float) + 16);
  __bf16* yb = xb + (size_t)N_ROWS * D_DIM;

  int cvt_blocks = 2 * N_ROWS * D_DIM / 8 / 256;  // 2048
  cvt_bf16_kernel<<<cvt_blocks, 256, 0, stream>>>(x, y, xb, yb, rowsum, done);

  infonce_gemm<<<4096, 256, 0, stream>>>(xb, yb, rowsum, diag, done, out);
}

// Round 5
// 157.201 us; speedup vs baseline: 2.9229x; 2.6803x over previous
//
#include <hip/hip_runtime.h>
#include <hip/hip_bf16.h>

#define N_ROWS 8192
#define D_DIM  256

// loss_i = log(sum_{j != i} exp(<x_i,y_j>/T)) - <x_i,y_i>/T ; out = mean_i loss_i
static constexpr float kScaleLog2 = 20.609929155556627f;  // (1/0.07) * log2(e)
static constexpr float kInvT      = 14.285714285714286f;  // 1/0.07

typedef __bf16 bf16x8 __attribute__((ext_vector_type(8)));
typedef float  f32x4  __attribute__((ext_vector_type(4)));

// async 16B global->LDS: LDS dest = wave-uniform base + lane*16
__device__ __forceinline__ void gl_lds16(const void* g, void* l) {
  __builtin_amdgcn_global_load_lds(
      (const __attribute__((address_space(1))) void*)g,
      (__attribute__((address_space(3))) void*)l, 16, 0, 0);
}

// ---------------- fp32 -> bf16 pre-convert + ws init ---------------------------
__global__ __launch_bounds__(256)
void cvt_bf16_kernel(const float* __restrict__ x, const float* __restrict__ y,
                     __bf16* __restrict__ xb, __bf16* __restrict__ yb,
                     float* __restrict__ rowsum) {
  if (blockIdx.x == 0) {
    for (int i = threadIdx.x; i < N_ROWS; i += 256) rowsum[i] = 0.f;
  }
  const int per_mat = N_ROWS * D_DIM / 8;  // 8 elements per thread
  int idx = blockIdx.x * blockDim.x + threadIdx.x;
  const float* src = x;
  __bf16* dst = xb;
  int i = idx;
  if (idx >= per_mat) { src = y; dst = yb; i = idx - per_mat; }
  float4 a = ((const float4*)src)[2 * (size_t)i];
  float4 b = ((const float4*)src)[2 * (size_t)i + 1];
  bf16x8 v;
  v[0] = (__bf16)a.x; v[1] = (__bf16)a.y; v[2] = (__bf16)a.z; v[3] = (__bf16)a.w;
  v[4] = (__bf16)b.x; v[5] = (__bf16)b.y; v[6] = (__bf16)b.z; v[7] = (__bf16)b.w;
  *(bf16x8*)(dst + (size_t)i * 8) = v;
}

// ---------------- fused GEMM + exp + row-sum ----------------------------------
// Block tile 128x128, BK=64, 256 threads = 4 waves (2x2), wave tile 64x64 via
// 4x4 MFMA 16x16x32 bf16. Staging via global_load_lds(16B), XOR swizzle
// applied on the GLOBAL source side (LDS image = R1's verified layout).
// NO device-scope fences in this kernel — agent-scope __threadfence() nukes
// the per-XCD L2 that serves the tile re-reads (R2-R4 regression).
__global__ __launch_bounds__(256, 3)
void infonce_gemm(const __bf16* __restrict__ X, const __bf16* __restrict__ Y,
                  float* __restrict__ rowsum, float* __restrict__ diag) {
  constexpr int BM = 128, BK = 64;
  __shared__ __bf16 Xs[BM * BK];   // 16 KB
  __shared__ __bf16 Ys[BM * BK];   // 16 KB

  // 8x8 supertiles over the 64x64 block grid (L2 locality)
  const int idx    = blockIdx.x;
  const int sb     = idx >> 6;
  const int within = idx & 63;
  const int bi = ((sb >> 3) << 3) + (within >> 3);
  const int bj = ((sb & 7) << 3) + (within & 7);

  const int t    = threadIdx.x;
  const int lane = t & 63;
  const int wave = t >> 6;        // 0..3
  const int wm   = wave >> 1;     // 0..1
  const int wn   = wave & 1;      // 0..1
  const int quad = lane >> 4;     // 0..3
  const int l15  = lane & 15;

  const __bf16* Xblk = X + (size_t)(bi * BM) * D_DIM;
  const __bf16* Yblk = Y + (size_t)(bj * BM) * D_DIM;

  f32x4 acc[4][4];
#pragma unroll
  for (int a = 0; a < 4; ++a)
#pragma unroll
    for (int b = 0; b < 4; ++b) acc[a][b] = (f32x4){0.f, 0.f, 0.f, 0.f};

  for (int kt = 0; kt < D_DIM / BK; ++kt) {
    if (kt) __syncthreads();
    const int k0 = kt * BK;
#pragma unroll
    for (int it = 0; it < 4; ++it) {
      const int c0  = (it * 4 + wave) * 64;  // wave-uniform slot base
      const int s   = c0 + lane;
      const int row = s >> 3;
      const int ch  = (s & 7) ^ (row & 7);   // inverse swizzle on global side
      const size_t goff = (size_t)row * D_DIM + k0 + ch * 8;
      gl_lds16(Xblk + goff, &Xs[c0 * 8]);
      gl_lds16(Yblk + goff, &Ys[c0 * 8]);
    }
    __syncthreads();

#pragma unroll
    for (int ks = 0; ks < 2; ++ks) {  // two k=32 steps per BK
      bf16x8 af[4], bfr[4];
#pragma unroll
      for (int mt = 0; mt < 4; ++mt) {
        int row = wm * 64 + mt * 16 + l15;
        int ch  = ks * 4 + quad;
        int chs = ch ^ (row & 7);
        af[mt] = *(const bf16x8*)(&Xs[row * BK + chs * 8]);
      }
#pragma unroll
      for (int nt = 0; nt < 4; ++nt) {
        int row = wn * 64 + nt * 16 + l15;
        int ch  = ks * 4 + quad;
        int chs = ch ^ (row & 7);
        bfr[nt] = *(const bf16x8*)(&Ys[row * BK + chs * 8]);
      }
#pragma unroll
      for (int mt = 0; mt < 4; ++mt)
#pragma unroll
        for (int nt = 0; nt < 4; ++nt)
          acc[mt][nt] = __builtin_amdgcn_mfma_f32_16x16x32_bf16(
              af[mt], bfr[nt], acc[mt][nt], 0, 0, 0);
    }
  }

  // epilogue: exp + row-sum (excluding diagonal), diag capture
  const int gi_base = bi * BM + wm * 64;
  const int gj_base = bj * BM + wn * 64;
#pragma unroll
  for (int mt = 0; mt < 4; ++mt) {
#pragma unroll
    for (int r = 0; r < 4; ++r) {
      const int gi = gi_base + mt * 16 + quad * 4 + r;
      float part = 0.f;
#pragma unroll
      for (int nt = 0; nt < 4; ++nt) {
        const int gj = gj_base + nt * 16 + l15;
        float s = acc[mt][nt][r];
        if (gi == gj) {
          diag[gi] = s;           // unique writer
        } else {
          part += exp2f(s * kScaleLog2);
        }
      }
      part += __shfl_xor(part, 1);
      part += __shfl_xor(part, 2);
      part += __shfl_xor(part, 4);
      part += __shfl_xor(part, 8);
      if (l15 == 0) atomicAdd(&rowsum[gi], part);
    }
  }
  // no fence: kernel-boundary release makes rowsum/diag visible to finalize
}

// ---------------- finalize: loss = mean(log(rowsum_i) - diag_i/T) --------------
__global__ __launch_bounds__(256)
void finalize_kernel(const float* __restrict__ rowsum,
                     const float* __restrict__ diag, float* __restrict__ out) {
  __shared__ float red[256];
  int t = threadIdx.x;
  float local = 0.f;
  for (int i = t; i < N_ROWS; i += 256)
    local += __logf(rowsum[i]) - diag[i] * kInvT;
  red[t] = local;
  __syncthreads();
  for (int s = 128; s > 0; s >>= 1) {
    if (t < s) red[t] += red[t + s];
    __syncthreads();
  }
  if (t == 0) out[0] = red[0] / (float)N_ROWS;
}

extern "C" void kernel_launch(void* const* d_in, const int* in_sizes, int n_in,
                              void* d_out, int out_size, void* d_ws, size_t ws_size,
                              hipStream_t stream) {
  const float* x = (const float*)d_in[0];
  const float* y = (const float*)d_in[1];
  float* out = (float*)d_out;

  // ws layout: rowsum[N] f32 | diag[N] f32 | pad | xb | yb
  float* rowsum = (float*)d_ws;
  float* diag   = rowsum + N_ROWS;
  __bf16* xb = (__bf16*)((char*)d_ws + 2 * N_ROWS * sizeof(float) + 16);
  __bf16* yb = xb + (size_t)N_ROWS * D_DIM;

  int cvt_blocks = 2 * N_ROWS * D_DIM / 8 / 256;  // 2048
  cvt_bf16_kernel<<<cvt_blocks, 256, 0, stream>>>(x, y, xb, yb, rowsum);

  infonce_gemm<<<4096, 256, 0, stream>>>(xb, yb, rowsum, diag);

  finalize_kernel<<<1, 256, 0, stream>>>(rowsum, diag, out);
}